// Round 1
// baseline (1300.202 us; speedup 1.0000x reference)
//
#include <hip/hip_runtime.h>

#define NEG_SLOPE 0.01f

constexpr int N_NODES_C = 50000;
constexpr int N_EDGES_C = 800000;

// out[n*D+d] = b[d]  (D is power of two, dmask = D-1)
__global__ __launch_bounds__(256) void init_bias_kernel(
    float* __restrict__ out, const float* __restrict__ b, int total, int dmask) {
  int idx = blockIdx.x * 256 + threadIdx.x;
  if (idx < total) out[idx] = b[idx & dmask];
}

// agg[dst[e]*D + d] += support[src[e]*D + d] * ew[e]
template <int D>
__global__ __launch_bounds__(256) void scatter_add_kernel(
    const float* __restrict__ support, const int* __restrict__ src,
    const int* __restrict__ dst, const float* __restrict__ ew,
    float* __restrict__ agg) {
  int idx = blockIdx.x * 256 + threadIdx.x;  // max 204.8M, fits int32
  int e = idx / D;
  int d = idx & (D - 1);
  if (e >= N_EDGES_C) return;
  float v = support[src[e] * D + d] * ew[e];
  atomicAdd(&agg[dst[e] * D + d], v);
}

// C[M,N] = op(A)[M,K] @ B[K,N], fp32, op = optional leaky_relu on A elements.
// Block tile 64x64, K-tile 16, 256 threads, 4x4 micro-tile per thread.
template <bool LRELU>
__global__ __launch_bounds__(256) void gemm64_kernel(
    const float* __restrict__ A, const float* __restrict__ B,
    float* __restrict__ C, int M, int N, int K) {
  constexpr int BM = 64, BN = 64, BK = 16;
  __shared__ float As[BK][BM];  // stored transposed: As[k][m]
  __shared__ float Bs[BK][BN];

  const int tid = threadIdx.x;
  const int tr = tid >> 4;  // 0..15 (M dir)
  const int tc = tid & 15;  // 0..15 (N dir)
  const int row0 = blockIdx.y * BM;
  const int col0 = blockIdx.x * BN;

  // load assignments
  const int am = tid >> 2;         // 0..63  A-tile row
  const int ak = (tid & 3) << 2;   // 0,4,8,12  A-tile col (float4 along K)
  const int bk = tid >> 4;         // 0..15  B-tile row
  const int bn = (tid & 15) << 2;  // 0..60  B-tile col (float4 along N)

  float acc[4][4] = {};

  for (int k0 = 0; k0 < K; k0 += BK) {
    float4 av = make_float4(0.f, 0.f, 0.f, 0.f);
    if (row0 + am < M) {
      av = *(const float4*)&A[(size_t)(row0 + am) * K + k0 + ak];
      if (LRELU) {
        av.x = av.x >= 0.f ? av.x : NEG_SLOPE * av.x;
        av.y = av.y >= 0.f ? av.y : NEG_SLOPE * av.y;
        av.z = av.z >= 0.f ? av.z : NEG_SLOPE * av.z;
        av.w = av.w >= 0.f ? av.w : NEG_SLOPE * av.w;
      }
    }
    float4 bv = *(const float4*)&B[(size_t)(k0 + bk) * N + col0 + bn];

    As[ak + 0][am] = av.x;
    As[ak + 1][am] = av.y;
    As[ak + 2][am] = av.z;
    As[ak + 3][am] = av.w;
    *(float4*)&Bs[bk][bn] = bv;
    __syncthreads();

#pragma unroll
    for (int kk = 0; kk < BK; ++kk) {
      float4 a = *(const float4*)&As[kk][tr << 2];
      float4 b = *(const float4*)&Bs[kk][tc << 2];
      acc[0][0] += a.x * b.x; acc[0][1] += a.x * b.y; acc[0][2] += a.x * b.z; acc[0][3] += a.x * b.w;
      acc[1][0] += a.y * b.x; acc[1][1] += a.y * b.y; acc[1][2] += a.y * b.z; acc[1][3] += a.y * b.w;
      acc[2][0] += a.z * b.x; acc[2][1] += a.z * b.y; acc[2][2] += a.z * b.z; acc[2][3] += a.z * b.w;
      acc[3][0] += a.w * b.x; acc[3][1] += a.w * b.y; acc[3][2] += a.w * b.z; acc[3][3] += a.w * b.w;
    }
    __syncthreads();
  }

#pragma unroll
  for (int i = 0; i < 4; ++i) {
    int r = row0 + (tr << 2) + i;
    if (r < M) {
      float4 o = make_float4(acc[i][0], acc[i][1], acc[i][2], acc[i][3]);
      *(float4*)&C[(size_t)r * N + col0 + (tc << 2)] = o;
    }
  }
}

__global__ __launch_bounds__(256) void lrelu_kernel(float* __restrict__ x, int total) {
  int idx = blockIdx.x * 256 + threadIdx.x;
  if (idx < total) {
    float v = x[idx];
    x[idx] = v >= 0.f ? v : NEG_SLOPE * v;
  }
}

extern "C" void kernel_launch(void* const* d_in, const int* in_sizes, int n_in,
                              void* d_out, int out_size, void* d_ws, size_t ws_size,
                              hipStream_t stream) {
  const float* x  = (const float*)d_in[0];   // [50000,256]
  const float* w1 = (const float*)d_in[1];   // [256,256]
  const float* b1 = (const float*)d_in[2];   // [256]
  const float* w2 = (const float*)d_in[3];   // [256,128]
  const float* b2 = (const float*)d_in[4];   // [128]
  const int*   src = (const int*)d_in[5];    // [800000]
  const int*   dst = (const int*)d_in[6];    // [800000]
  const float* ew  = (const float*)d_in[7];  // [800000]
  float* out = (float*)d_out;                // [50000,128]

  // workspace: support1 (12.8M fl) | agg1 (12.8M fl); support2 reuses support1's slot
  float* support1 = (float*)d_ws;
  float* agg1 = support1 + (size_t)N_NODES_C * 256;
  float* support2 = support1;

  const int M = N_NODES_C;

  // ---- layer 1 ----
  {
    dim3 grid(256 / 64, (M + 63) / 64);
    gemm64_kernel<false><<<grid, 256, 0, stream>>>(x, w1, support1, M, 256, 256);
  }
  {
    int total = M * 256;
    init_bias_kernel<<<(total + 255) / 256, 256, 0, stream>>>(agg1, b1, total, 255);
  }
  {
    int total = N_EDGES_C * 256;
    scatter_add_kernel<256><<<total / 256, 256, 0, stream>>>(support1, src, dst, ew, agg1);
  }

  // ---- layer 2 (leaky_relu fused into A-load of GEMM2) ----
  {
    dim3 grid(128 / 64, (M + 63) / 64);
    gemm64_kernel<true><<<grid, 256, 0, stream>>>(agg1, w2, support2, M, 128, 256);
  }
  {
    int total = M * 128;
    init_bias_kernel<<<(total + 255) / 256, 256, 0, stream>>>(out, b2, total, 127);
  }
  {
    int total = N_EDGES_C * 128;
    scatter_add_kernel<128><<<total / 256, 256, 0, stream>>>(support2, src, dst, ew, out);
  }
  {
    int total = M * 128;
    lrelu_kernel<<<(total + 255) / 256, 256, 0, stream>>>(out, total);
  }
}

// Round 2
// 622.024 us; speedup vs baseline: 2.0903x; 2.0903x over previous
//
#include <hip/hip_runtime.h>

#define NEG_SLOPE 0.01f

constexpr int N_NODES_C = 50000;
constexpr int N_EDGES_C = 800000;

// ---------- CSR build ----------

__global__ __launch_bounds__(256) void zero_counts_kernel(int* __restrict__ counts) {
  int i = blockIdx.x * 256 + threadIdx.x;
  if (i < N_NODES_C) counts[i] = 0;
}

__global__ __launch_bounds__(256) void histogram_kernel(const int* __restrict__ dst,
                                                        int* __restrict__ counts) {
  int e = blockIdx.x * 256 + threadIdx.x;
  if (e < N_EDGES_C) atomicAdd(&counts[dst[e]], 1);
}

// Single-block exclusive scan of 50000 counts -> row_ptr[50001], cursor[50000]
constexpr int SCAN_T = 1024;
constexpr int SCAN_CHUNK = (N_NODES_C + SCAN_T - 1) / SCAN_T;  // 49

__global__ __launch_bounds__(1024) void scan_kernel(const int* __restrict__ counts,
                                                    int* __restrict__ row_ptr,
                                                    int* __restrict__ cursor) {
  __shared__ int sums[SCAN_T];
  const int t = threadIdx.x;
  const int begin = t * SCAN_CHUNK;
  const int end = min(begin + SCAN_CHUNK, N_NODES_C);
  int local = 0;
  for (int i = begin; i < end; ++i) local += counts[i];
  sums[t] = local;
  __syncthreads();
  for (int off = 1; off < SCAN_T; off <<= 1) {
    int v = (t >= off) ? sums[t - off] : 0;
    __syncthreads();
    if (t >= off) sums[t] += v;
    __syncthreads();
  }
  int running = (t == 0) ? 0 : sums[t - 1];
  for (int i = begin; i < end; ++i) {
    row_ptr[i] = running;
    cursor[i] = running;
    running += counts[i];
  }
  if (t == SCAN_T - 1) row_ptr[N_NODES_C] = N_EDGES_C;
}

// Bucket-fill: sorted-by-dst copies of src and ew
__global__ __launch_bounds__(256) void fill_kernel(const int* __restrict__ src,
                                                   const int* __restrict__ dst,
                                                   const float* __restrict__ ew,
                                                   int* __restrict__ cursor,
                                                   int* __restrict__ s_src,
                                                   float* __restrict__ s_ew) {
  int e = blockIdx.x * 256 + threadIdx.x;
  if (e < N_EDGES_C) {
    int p = atomicAdd(&cursor[dst[e]], 1);
    s_src[p] = src[e];
    s_ew[p] = ew[e];
  }
}

// ---------- gather aggregation: out[n,:] = bias + sum_{e in in(n)} support[src_e,:]*ew_e ----------
// one block per node, one thread per dim; edge meta staged through LDS in chunks of 64.
template <int D, bool LRELU>
__global__ __launch_bounds__(D) void agg_gather_kernel(
    const float* __restrict__ support, const int* __restrict__ s_src,
    const float* __restrict__ s_ew, const int* __restrict__ row_ptr,
    const float* __restrict__ bias, float* __restrict__ out) {
  __shared__ int ls[64];
  __shared__ float lw[64];
  const int n = blockIdx.x;
  const int d = threadIdx.x;
  const int start = row_ptr[n];
  const int end = row_ptr[n + 1];
  float acc = bias[d];
  for (int j0 = start; j0 < end; j0 += 64) {
    const int cnt = min(64, end - j0);
    if (threadIdx.x < 64) {
      if ((int)threadIdx.x < cnt) ls[threadIdx.x] = s_src[j0 + threadIdx.x];
    } else if (threadIdx.x < 128) {
      int t = threadIdx.x - 64;
      if (t < cnt) lw[t] = s_ew[j0 + t];
    }
    __syncthreads();
#pragma unroll 4
    for (int c = 0; c < cnt; ++c)
      acc += support[(size_t)ls[c] * D + d] * lw[c];
    __syncthreads();
  }
  float v = acc;
  if (LRELU) v = v >= 0.f ? v : NEG_SLOPE * v;
  out[(size_t)n * D + d] = v;
}

// ---------- fp32 GEMM (unchanged from R0) ----------
template <bool LRELU>
__global__ __launch_bounds__(256) void gemm64_kernel(
    const float* __restrict__ A, const float* __restrict__ B,
    float* __restrict__ C, int M, int N, int K) {
  constexpr int BM = 64, BN = 64, BK = 16;
  __shared__ float As[BK][BM];
  __shared__ float Bs[BK][BN];

  const int tid = threadIdx.x;
  const int tr = tid >> 4;
  const int tc = tid & 15;
  const int row0 = blockIdx.y * BM;
  const int col0 = blockIdx.x * BN;

  const int am = tid >> 2;
  const int ak = (tid & 3) << 2;
  const int bk = tid >> 4;
  const int bn = (tid & 15) << 2;

  float acc[4][4] = {};

  for (int k0 = 0; k0 < K; k0 += BK) {
    float4 av = make_float4(0.f, 0.f, 0.f, 0.f);
    if (row0 + am < M) {
      av = *(const float4*)&A[(size_t)(row0 + am) * K + k0 + ak];
      if (LRELU) {
        av.x = av.x >= 0.f ? av.x : NEG_SLOPE * av.x;
        av.y = av.y >= 0.f ? av.y : NEG_SLOPE * av.y;
        av.z = av.z >= 0.f ? av.z : NEG_SLOPE * av.z;
        av.w = av.w >= 0.f ? av.w : NEG_SLOPE * av.w;
      }
    }
    float4 bv = *(const float4*)&B[(size_t)(k0 + bk) * N + col0 + bn];

    As[ak + 0][am] = av.x;
    As[ak + 1][am] = av.y;
    As[ak + 2][am] = av.z;
    As[ak + 3][am] = av.w;
    *(float4*)&Bs[bk][bn] = bv;
    __syncthreads();

#pragma unroll
    for (int kk = 0; kk < BK; ++kk) {
      float4 a = *(const float4*)&As[kk][tr << 2];
      float4 b = *(const float4*)&Bs[kk][tc << 2];
      acc[0][0] += a.x * b.x; acc[0][1] += a.x * b.y; acc[0][2] += a.x * b.z; acc[0][3] += a.x * b.w;
      acc[1][0] += a.y * b.x; acc[1][1] += a.y * b.y; acc[1][2] += a.y * b.z; acc[1][3] += a.y * b.w;
      acc[2][0] += a.z * b.x; acc[2][1] += a.z * b.y; acc[2][2] += a.z * b.z; acc[2][3] += a.z * b.w;
      acc[3][0] += a.w * b.x; acc[3][1] += a.w * b.y; acc[3][2] += a.w * b.z; acc[3][3] += a.w * b.w;
    }
    __syncthreads();
  }

#pragma unroll
  for (int i = 0; i < 4; ++i) {
    int r = row0 + (tr << 2) + i;
    if (r < M) {
      float4 o = make_float4(acc[i][0], acc[i][1], acc[i][2], acc[i][3]);
      *(float4*)&C[(size_t)r * N + col0 + (tc << 2)] = o;
    }
  }
}

extern "C" void kernel_launch(void* const* d_in, const int* in_sizes, int n_in,
                              void* d_out, int out_size, void* d_ws, size_t ws_size,
                              hipStream_t stream) {
  const float* x  = (const float*)d_in[0];   // [50000,256]
  const float* w1 = (const float*)d_in[1];   // [256,256]
  const float* b1 = (const float*)d_in[2];   // [256]
  const float* w2 = (const float*)d_in[3];   // [256,128]
  const float* b2 = (const float*)d_in[4];   // [128]
  const int*   src = (const int*)d_in[5];    // [800000]
  const int*   dst = (const int*)d_in[6];    // [800000]
  const float* ew  = (const float*)d_in[7];  // [800000]
  float* out = (float*)d_out;                // [50000,128]

  // workspace layout (floats/ints, all 4B-aligned; support/agg 16B-aligned)
  float* support1 = (float*)d_ws;                          // 12.8M floats
  float* agg1     = support1 + (size_t)N_NODES_C * 256;    // 12.8M floats
  int*   counts   = (int*)(agg1 + (size_t)N_NODES_C * 256);// 50000
  int*   cursor   = counts + N_NODES_C;                    // 50000
  int*   row_ptr  = cursor + N_NODES_C;                    // 50001
  int*   s_src    = row_ptr + (N_NODES_C + 1);             // 800000
  float* s_ew     = (float*)(s_src + N_EDGES_C);           // 800000
  float* support2 = support1;                              // reuse (needs 6.4M floats)

  const int M = N_NODES_C;
  const int EB = (N_EDGES_C + 255) / 256;

  // ---- CSR build (dst-sorted edge list) ----
  zero_counts_kernel<<<(N_NODES_C + 255) / 256, 256, 0, stream>>>(counts);
  histogram_kernel<<<EB, 256, 0, stream>>>(dst, counts);
  scan_kernel<<<1, SCAN_T, 0, stream>>>(counts, row_ptr, cursor);
  fill_kernel<<<EB, 256, 0, stream>>>(src, dst, ew, cursor, s_src, s_ew);

  // ---- layer 1 ----
  {
    dim3 grid(256 / 64, (M + 63) / 64);
    gemm64_kernel<false><<<grid, 256, 0, stream>>>(x, w1, support1, M, 256, 256);
  }
  agg_gather_kernel<256, false><<<M, 256, 0, stream>>>(support1, s_src, s_ew, row_ptr, b1, agg1);

  // ---- layer 2 (leaky_relu of layer-1 output fused into GEMM2 A-load) ----
  {
    dim3 grid(128 / 64, (M + 63) / 64);
    gemm64_kernel<true><<<grid, 256, 0, stream>>>(agg1, w2, support2, M, 128, 256);
  }
  agg_gather_kernel<128, true><<<M, 128, 0, stream>>>(support2, s_src, s_ew, row_ptr, b2, out);
}

// Round 3
// 461.513 us; speedup vs baseline: 2.8173x; 1.3478x over previous
//
#include <hip/hip_runtime.h>

#define NEG_SLOPE 0.01f

constexpr int N_NODES_C = 50000;
constexpr int N_EDGES_C = 800000;
constexpr int M_PAD = 50048;  // 391 * 128

typedef short bf16x8 __attribute__((ext_vector_type(8)));
typedef float f32x4 __attribute__((ext_vector_type(4)));

__device__ inline unsigned short f2bf(float f) {
  unsigned int u = __float_as_uint(f);
  u += 0x7FFF + ((u >> 16) & 1);  // round-to-nearest-even
  return (unsigned short)(u >> 16);
}
__device__ inline float bf2f(unsigned int h16) {
  return __uint_as_float(h16 << 16);
}

// ---------------- CSR build ----------------

__global__ __launch_bounds__(256) void zero_counts_kernel(int* __restrict__ counts) {
  int i = blockIdx.x * 256 + threadIdx.x;
  if (i < N_NODES_C) counts[i] = 0;
}

__global__ __launch_bounds__(256) void histogram_kernel(const int* __restrict__ dst,
                                                        int* __restrict__ counts) {
  int e = blockIdx.x * 256 + threadIdx.x;
  if (e < N_EDGES_C) atomicAdd(&counts[dst[e]], 1);
}

constexpr int SCAN_T = 1024;
constexpr int SCAN_CHUNK = (N_NODES_C + SCAN_T - 1) / SCAN_T;  // 49

__global__ __launch_bounds__(1024) void scan_kernel(const int* __restrict__ counts,
                                                    int* __restrict__ row_ptr,
                                                    int* __restrict__ cursor) {
  __shared__ int sums[SCAN_T];
  const int t = threadIdx.x;
  const int begin = t * SCAN_CHUNK;
  const int end = min(begin + SCAN_CHUNK, N_NODES_C);
  int local = 0;
  for (int i = begin; i < end; ++i) local += counts[i];
  sums[t] = local;
  __syncthreads();
  for (int off = 1; off < SCAN_T; off <<= 1) {
    int v = (t >= off) ? sums[t - off] : 0;
    __syncthreads();
    if (t >= off) sums[t] += v;
    __syncthreads();
  }
  int running = (t == 0) ? 0 : sums[t - 1];
  for (int i = begin; i < end; ++i) {
    row_ptr[i] = running;
    cursor[i] = running;
    running += counts[i];
  }
  if (t == SCAN_T - 1) row_ptr[N_NODES_C] = N_EDGES_C;
}

__global__ __launch_bounds__(256) void fill_kernel(const int* __restrict__ src,
                                                   const int* __restrict__ dst,
                                                   const float* __restrict__ ew,
                                                   int* __restrict__ cursor,
                                                   int* __restrict__ s_src,
                                                   float* __restrict__ s_ew) {
  int e = blockIdx.x * 256 + threadIdx.x;
  if (e < N_EDGES_C) {
    int p = atomicAdd(&cursor[dst[e]], 1);
    s_src[p] = src[e];
    s_ew[p] = ew[e];
  }
}

// ---------------- conversions ----------------

// x fp32 [50000][256] -> bf16 [M_PAD][256], pad rows zero. one thread = 8 elems
__global__ __launch_bounds__(256) void conv_x_kernel(const float* __restrict__ x,
                                                     unsigned short* __restrict__ xb) {
  int idx = blockIdx.x * 256 + threadIdx.x;
  if (idx >= M_PAD * 32) return;
  int row = idx >> 5;
  int c8 = (idx & 31) << 3;
  uint4 v;
  if (row < N_NODES_C) {
    const float4* p = (const float4*)(x + (size_t)row * 256 + c8);
    float4 a = p[0], b = p[1];
    v.x = f2bf(a.x) | ((unsigned)f2bf(a.y) << 16);
    v.y = f2bf(a.z) | ((unsigned)f2bf(a.w) << 16);
    v.z = f2bf(b.x) | ((unsigned)f2bf(b.y) << 16);
    v.w = f2bf(b.z) | ((unsigned)f2bf(b.w) << 16);
  } else {
    v = make_uint4(0, 0, 0, 0);
  }
  *(uint4*)(xb + (size_t)row * 256 + c8) = v;
}

// w [K][N] fp32 -> wT [N][K] bf16
__global__ __launch_bounds__(256) void conv_wT_kernel(const float* __restrict__ w,
                                                      unsigned short* __restrict__ wT,
                                                      int K, int N) {
  int idx = blockIdx.x * 256 + threadIdx.x;
  if (idx >= K * N) return;
  int n = idx / K, k = idx - n * K;
  wT[idx] = f2bf(w[(size_t)k * N + n]);
}

// ---------------- bf16 MFMA GEMM: C[M_PAD][N] = A[M_PAD][256] @ BT[N][256]^T ----------------
// 128x128 block tile, BK=32, 4 waves (2x2), each wave 4x4 tiles of 16x16x32.

#define GLOAD_LDS16(g, l)                                              \
  __builtin_amdgcn_global_load_lds(                                    \
      (__attribute__((address_space(1))) void*)(g),                    \
      (__attribute__((address_space(3))) void*)(l), 16, 0, 0)

__global__ __launch_bounds__(256) void gemm_bf16_kernel(
    const unsigned short* __restrict__ A,   // [M_PAD][256] bf16
    const unsigned short* __restrict__ BT,  // [N][256] bf16
    unsigned short* __restrict__ C,         // [M_PAD][N] bf16
    int N) {
  constexpr int K = 256;
  __shared__ short Asm[128 * 32];
  __shared__ short Bsm[128 * 32];
  const int tid = threadIdx.x;
  const int lane = tid & 63, wave = tid >> 6;
  const int wm = wave & 1, wn = wave >> 1;
  const int row0 = blockIdx.y * 128, col0 = blockIdx.x * 128;

  // staging geometry: 8 chunks of 1KB per tile, 2 per wave
  const int ch0 = wave * 2, ch1 = wave * 2 + 1;
  const int o0 = ch0 * 512 + lane * 8;
  const int o1 = ch1 * 512 + lane * 8;
  const int r0 = o0 >> 5, c0 = o0 & 31;
  const int r1 = o1 >> 5, c1 = o1 & 31;

  f32x4 acc[4][4] = {};

  for (int k0 = 0; k0 < K; k0 += 32) {
    GLOAD_LDS16(A + (size_t)(row0 + r0) * K + k0 + c0, &Asm[ch0 * 512]);
    GLOAD_LDS16(A + (size_t)(row0 + r1) * K + k0 + c1, &Asm[ch1 * 512]);
    GLOAD_LDS16(BT + (size_t)(col0 + r0) * K + k0 + c0, &Bsm[ch0 * 512]);
    GLOAD_LDS16(BT + (size_t)(col0 + r1) * K + k0 + c1, &Bsm[ch1 * 512]);
    __builtin_amdgcn_s_waitcnt(0);
    __syncthreads();

    bf16x8 af[4], bf[4];
#pragma unroll
    for (int mt = 0; mt < 4; ++mt)
      af[mt] = *(const bf16x8*)&Asm[(wm * 64 + mt * 16 + (lane & 15)) * 32 + (lane >> 4) * 8];
#pragma unroll
    for (int nt = 0; nt < 4; ++nt)
      bf[nt] = *(const bf16x8*)&Bsm[(wn * 64 + nt * 16 + (lane & 15)) * 32 + (lane >> 4) * 8];
#pragma unroll
    for (int mt = 0; mt < 4; ++mt)
#pragma unroll
      for (int nt = 0; nt < 4; ++nt)
        acc[mt][nt] = __builtin_amdgcn_mfma_f32_16x16x32_bf16(af[mt], bf[nt], acc[mt][nt], 0, 0, 0);
    __syncthreads();
  }

  const int cl = lane & 15, rq = (lane >> 4) * 4;
#pragma unroll
  for (int mt = 0; mt < 4; ++mt) {
    const int rbase = row0 + wm * 64 + mt * 16 + rq;
#pragma unroll
    for (int nt = 0; nt < 4; ++nt) {
      const int col = col0 + wn * 64 + nt * 16 + cl;
#pragma unroll
      for (int i = 0; i < 4; ++i)
        C[(size_t)(rbase + i) * N + col] = f2bf(acc[mt][nt][i]);
    }
  }
}

// ---------------- gather aggregation, wave-per-node ----------------
// out[n,:] = lrelu(bias + sum_e support[src_e,:]*ew_e); OUT_BF16 -> bf16 store (layer 1)

template <int D, bool OUT_BF16>
__global__ __launch_bounds__(256) void agg_kernel(
    const unsigned short* __restrict__ support, const int* __restrict__ s_src,
    const float* __restrict__ s_ew, const int* __restrict__ row_ptr,
    const float* __restrict__ bias, unsigned short* __restrict__ out_bf,
    float* __restrict__ out_f, int n_total) {
  constexpr int VEC = D / 64;
  const int lane = threadIdx.x & 63;
  const int n = blockIdx.x * 4 + (threadIdx.x >> 6);
  if (n >= n_total) return;
  const bool valid = n < N_NODES_C;

  float acc[VEC];
#pragma unroll
  for (int j = 0; j < VEC; ++j) acc[j] = 0.f;

  if (valid) {
    const int start = row_ptr[n];
    const int end = row_ptr[n + 1];
    for (int j0 = start; j0 < end; j0 += 64) {
      const int cnt = min(64, end - j0);
      int e = 0;
      float w = 0.f;
      if (lane < cnt) {
        e = s_src[j0 + lane];
        w = s_ew[j0 + lane];
      }
#pragma unroll 4
      for (int c = 0; c < cnt; ++c) {
        const int s = __shfl(e, c);
        const float wt = __shfl(w, c);
        if (VEC == 4) {
          uint2 v = *(const uint2*)(support + (size_t)s * D + lane * 4);
          acc[0] += bf2f(v.x & 0xffffu) * wt;
          acc[1] += bf2f(v.x >> 16) * wt;
          acc[2] += bf2f(v.y & 0xffffu) * wt;
          acc[3] += bf2f(v.y >> 16) * wt;
        } else {
          unsigned v = *(const unsigned*)(support + (size_t)s * D + lane * 2);
          acc[0] += bf2f(v & 0xffffu) * wt;
          acc[1] += bf2f(v >> 16) * wt;
        }
      }
    }
  }

  if (OUT_BF16) {
    unsigned short o[VEC];
#pragma unroll
    for (int j = 0; j < VEC; ++j) {
      if (valid) {
        float v = acc[j] + bias[lane * VEC + j];
        v = v >= 0.f ? v : NEG_SLOPE * v;
        o[j] = f2bf(v);
      } else {
        o[j] = 0;
      }
    }
    if (VEC == 4) {
      uint2 pk;
      pk.x = o[0] | ((unsigned)o[1] << 16);
      pk.y = o[2] | ((unsigned)o[3] << 16);
      *(uint2*)(out_bf + (size_t)n * D + lane * 4) = pk;
    } else {
      *(unsigned*)(out_bf + (size_t)n * D + lane * 2) = o[0] | ((unsigned)o[1] << 16);
    }
  } else {
#pragma unroll
    for (int j = 0; j < VEC; ++j) {
      float v = acc[j] + bias[lane * VEC + j];
      acc[j] = v >= 0.f ? v : NEG_SLOPE * v;
    }
    if (VEC == 2) {
      *(float2*)(out_f + (size_t)n * D + lane * 2) = make_float2(acc[0], acc[1]);
    } else {
      *(float4*)(out_f + (size_t)n * D + lane * 4) =
          make_float4(acc[0], acc[1], acc[2], acc[3]);
    }
  }
}

// ---------------- launch ----------------

extern "C" void kernel_launch(void* const* d_in, const int* in_sizes, int n_in,
                              void* d_out, int out_size, void* d_ws, size_t ws_size,
                              hipStream_t stream) {
  const float* x  = (const float*)d_in[0];   // [50000,256]
  const float* w1 = (const float*)d_in[1];   // [256,256]
  const float* b1 = (const float*)d_in[2];   // [256]
  const float* w2 = (const float*)d_in[3];   // [256,128]
  const float* b2 = (const float*)d_in[4];   // [128]
  const int*   src = (const int*)d_in[5];    // [800000]
  const int*   dst = (const int*)d_in[6];    // [800000]
  const float* ew  = (const float*)d_in[7];  // [800000]
  float* out = (float*)d_out;                // [50000,128]

  // workspace layout (bf16 tables then CSR); ~97 MB total
  unsigned short* xb   = (unsigned short*)d_ws;              // M_PAD*256
  unsigned short* a2b  = xb + (size_t)M_PAD * 256;           // M_PAD*256
  unsigned short* sup1 = a2b + (size_t)M_PAD * 256;          // M_PAD*256
  unsigned short* sup2 = sup1 + (size_t)M_PAD * 256;         // M_PAD*128
  unsigned short* w1T  = sup2 + (size_t)M_PAD * 128;         // 256*256
  unsigned short* w2T  = w1T + 256 * 256;                    // 128*256
  int* counts  = (int*)(w2T + 128 * 256);                    // 50000
  int* cursor  = counts + N_NODES_C;                         // 50000
  int* row_ptr = cursor + N_NODES_C;                         // 50001
  int* s_src   = row_ptr + (N_NODES_C + 1);                  // 800000
  float* s_ew  = (float*)(s_src + N_EDGES_C);                // 800000

  const int EB = (N_EDGES_C + 255) / 256;

  // CSR build
  zero_counts_kernel<<<(N_NODES_C + 255) / 256, 256, 0, stream>>>(counts);
  histogram_kernel<<<EB, 256, 0, stream>>>(dst, counts);
  scan_kernel<<<1, SCAN_T, 0, stream>>>(counts, row_ptr, cursor);
  fill_kernel<<<EB, 256, 0, stream>>>(src, dst, ew, cursor, s_src, s_ew);

  // conversions
  conv_x_kernel<<<(M_PAD * 32 + 255) / 256, 256, 0, stream>>>(x, xb);
  conv_wT_kernel<<<(256 * 256 + 255) / 256, 256, 0, stream>>>(w1, w1T, 256, 256);
  conv_wT_kernel<<<(128 * 256 + 255) / 256, 256, 0, stream>>>(w2, w2T, 256, 128);

  // layer 1: support1 = x @ w1 (bf16), agg -> a2b = bf16(lrelu(agg + b1))
  gemm_bf16_kernel<<<dim3(2, M_PAD / 128), 256, 0, stream>>>(xb, w1T, sup1, 256);
  agg_kernel<256, true><<<M_PAD / 4, 256, 0, stream>>>(sup1, s_src, s_ew, row_ptr,
                                                       b1, a2b, nullptr, M_PAD);

  // layer 2: support2 = a2 @ w2 (bf16), agg -> out = lrelu(agg + b2) fp32
  gemm_bf16_kernel<<<dim3(1, M_PAD / 128), 256, 0, stream>>>(a2b, w2T, sup2, 128);
  agg_kernel<128, false><<<N_NODES_C / 4, 256, 0, stream>>>(sup2, s_src, s_ew, row_ptr,
                                                            b2, nullptr, out, N_NODES_C);
}

// Round 4
// 359.942 us; speedup vs baseline: 3.6123x; 1.2822x over previous
//
#include <hip/hip_runtime.h>

#define NEG_SLOPE 0.01f

constexpr int N_NODES_C = 50000;
constexpr int N_EDGES_C = 800000;
constexpr int M_PAD = 50048;  // 391 * 128

typedef short bf16x8 __attribute__((ext_vector_type(8)));
typedef float f32x4 __attribute__((ext_vector_type(4)));

__device__ inline unsigned short f2bf(float f) {
  unsigned int u = __float_as_uint(f);
  u += 0x7FFF + ((u >> 16) & 1);  // round-to-nearest-even
  return (unsigned short)(u >> 16);
}
__device__ inline float bf2f(unsigned int h16) {
  return __uint_as_float(h16 << 16);
}

// ---------------- CSR build ----------------

__global__ __launch_bounds__(256) void histogram_kernel(const int* __restrict__ dst,
                                                        int* __restrict__ counts) {
  int e = blockIdx.x * 256 + threadIdx.x;
  if (e < N_EDGES_C) atomicAdd(&counts[dst[e]], 1);
}

// hierarchical scan: 196 block-scans -> scan of block sums -> offset add
constexpr int N_SCAN_BLKS = (N_NODES_C + 255) / 256;  // 196

__global__ __launch_bounds__(256) void scan_phase_a(const int* __restrict__ counts,
                                                    int* __restrict__ partial,
                                                    int* __restrict__ blk_sums) {
  __shared__ int s[256];
  const int t = threadIdx.x;
  const int i = blockIdx.x * 256 + t;
  const int v = (i < N_NODES_C) ? counts[i] : 0;
  s[t] = v;
  __syncthreads();
  for (int off = 1; off < 256; off <<= 1) {
    int u = (t >= off) ? s[t - off] : 0;
    __syncthreads();
    s[t] += u;
    __syncthreads();
  }
  if (i < N_NODES_C) partial[i] = s[t] - v;  // exclusive within block
  if (t == 255) blk_sums[blockIdx.x] = s[255];
}

__global__ __launch_bounds__(256) void scan_phase_b(const int* __restrict__ blk_sums,
                                                    int* __restrict__ blk_off) {
  __shared__ int s[256];
  const int t = threadIdx.x;
  const int v = (t < N_SCAN_BLKS) ? blk_sums[t] : 0;
  s[t] = v;
  __syncthreads();
  for (int off = 1; off < 256; off <<= 1) {
    int u = (t >= off) ? s[t - off] : 0;
    __syncthreads();
    s[t] += u;
    __syncthreads();
  }
  if (t < N_SCAN_BLKS) blk_off[t] = s[t] - v;  // exclusive
}

__global__ __launch_bounds__(256) void scan_phase_c(const int* __restrict__ partial,
                                                    const int* __restrict__ blk_off,
                                                    int* __restrict__ row_ptr,
                                                    int* __restrict__ cursor) {
  const int i = blockIdx.x * 256 + threadIdx.x;
  if (i < N_NODES_C) {
    const int r = partial[i] + blk_off[blockIdx.x];
    row_ptr[i] = r;
    cursor[i] = r;
  }
  if (i == 0) row_ptr[N_NODES_C] = N_EDGES_C;
}

__global__ __launch_bounds__(256) void fill_kernel(const int* __restrict__ src,
                                                   const int* __restrict__ dst,
                                                   const float* __restrict__ ew,
                                                   int* __restrict__ cursor,
                                                   int* __restrict__ s_src,
                                                   float* __restrict__ s_ew) {
  int e = blockIdx.x * 256 + threadIdx.x;
  if (e < N_EDGES_C) {
    int p = atomicAdd(&cursor[dst[e]], 1);
    s_src[p] = src[e];
    s_ew[p] = ew[e];
  }
}

// ---------------- conversions ----------------

// x fp32 [50000][256] -> bf16 [M_PAD][256], pad rows zero. one thread = 8 elems
__global__ __launch_bounds__(256) void conv_x_kernel(const float* __restrict__ x,
                                                     unsigned short* __restrict__ xb) {
  int idx = blockIdx.x * 256 + threadIdx.x;
  if (idx >= M_PAD * 32) return;
  int row = idx >> 5;
  int c8 = (idx & 31) << 3;
  uint4 v;
  if (row < N_NODES_C) {
    const float4* p = (const float4*)(x + (size_t)row * 256 + c8);
    float4 a = p[0], b = p[1];
    v.x = f2bf(a.x) | ((unsigned)f2bf(a.y) << 16);
    v.y = f2bf(a.z) | ((unsigned)f2bf(a.w) << 16);
    v.z = f2bf(b.x) | ((unsigned)f2bf(b.y) << 16);
    v.w = f2bf(b.z) | ((unsigned)f2bf(b.w) << 16);
  } else {
    v = make_uint4(0, 0, 0, 0);
  }
  *(uint4*)(xb + (size_t)row * 256 + c8) = v;
}

// w [K][N] fp32 -> wT [N][K] bf16
__global__ __launch_bounds__(256) void conv_wT_kernel(const float* __restrict__ w,
                                                      unsigned short* __restrict__ wT,
                                                      int K, int N) {
  int idx = blockIdx.x * 256 + threadIdx.x;
  if (idx >= K * N) return;
  int n = idx / K, k = idx - n * K;
  wT[idx] = f2bf(w[(size_t)k * N + n]);
}

// ---------------- bf16 MFMA GEMM: C[M_PAD][N] = A[M_PAD][256] @ BT[N][256]^T ----------------
// 128x128 block tile, BK=32, 4 waves (2x2), each wave 4x4 tiles of 16x16x32.

#define GLOAD_LDS16(g, l)                                              \
  __builtin_amdgcn_global_load_lds(                                    \
      (__attribute__((address_space(1))) void*)(g),                    \
      (__attribute__((address_space(3))) void*)(l), 16, 0, 0)

__global__ __launch_bounds__(256) void gemm_bf16_kernel(
    const unsigned short* __restrict__ A,   // [M_PAD][256] bf16
    const unsigned short* __restrict__ BT,  // [N][256] bf16
    unsigned short* __restrict__ C,         // [M_PAD][N] bf16
    int N) {
  constexpr int K = 256;
  __shared__ short Asm[128 * 32];
  __shared__ short Bsm[128 * 32];
  const int tid = threadIdx.x;
  const int lane = tid & 63, wave = tid >> 6;
  const int wm = wave & 1, wn = wave >> 1;
  const int row0 = blockIdx.y * 128, col0 = blockIdx.x * 128;

  // staging geometry: 8 chunks of 1KB per tile, 2 per wave
  const int ch0 = wave * 2, ch1 = wave * 2 + 1;
  const int o0 = ch0 * 512 + lane * 8;
  const int o1 = ch1 * 512 + lane * 8;
  const int r0 = o0 >> 5, c0 = o0 & 31;
  const int r1 = o1 >> 5, c1 = o1 & 31;

  f32x4 acc[4][4] = {};

  for (int k0 = 0; k0 < K; k0 += 32) {
    GLOAD_LDS16(A + (size_t)(row0 + r0) * K + k0 + c0, &Asm[ch0 * 512]);
    GLOAD_LDS16(A + (size_t)(row0 + r1) * K + k0 + c1, &Asm[ch1 * 512]);
    GLOAD_LDS16(BT + (size_t)(col0 + r0) * K + k0 + c0, &Bsm[ch0 * 512]);
    GLOAD_LDS16(BT + (size_t)(col0 + r1) * K + k0 + c1, &Bsm[ch1 * 512]);
    __builtin_amdgcn_s_waitcnt(0);
    __syncthreads();

    bf16x8 af[4], bf[4];
#pragma unroll
    for (int mt = 0; mt < 4; ++mt)
      af[mt] = *(const bf16x8*)&Asm[(wm * 64 + mt * 16 + (lane & 15)) * 32 + (lane >> 4) * 8];
#pragma unroll
    for (int nt = 0; nt < 4; ++nt)
      bf[nt] = *(const bf16x8*)&Bsm[(wn * 64 + nt * 16 + (lane & 15)) * 32 + (lane >> 4) * 8];
#pragma unroll
    for (int mt = 0; mt < 4; ++mt)
#pragma unroll
      for (int nt = 0; nt < 4; ++nt)
        acc[mt][nt] = __builtin_amdgcn_mfma_f32_16x16x32_bf16(af[mt], bf[nt], acc[mt][nt], 0, 0, 0);
    __syncthreads();
  }

  const int cl = lane & 15, rq = (lane >> 4) * 4;
#pragma unroll
  for (int mt = 0; mt < 4; ++mt) {
    const int rbase = row0 + wm * 64 + mt * 16 + rq;
#pragma unroll
    for (int nt = 0; nt < 4; ++nt) {
      const int col = col0 + wn * 64 + nt * 16 + cl;
#pragma unroll
      for (int i = 0; i < 4; ++i)
        C[(size_t)(rbase + i) * N + col] = f2bf(acc[mt][nt][i]);
    }
  }
}

// ---------------- gather aggregation, wave-per-node ----------------
// out[n,:] = lrelu(bias + sum_e support[src_e,:]*ew_e); OUT_BF16 -> bf16 store (layer 1)

template <int D, bool OUT_BF16>
__global__ __launch_bounds__(256) void agg_kernel(
    const unsigned short* __restrict__ support, const int* __restrict__ s_src,
    const float* __restrict__ s_ew, const int* __restrict__ row_ptr,
    const float* __restrict__ bias, unsigned short* __restrict__ out_bf,
    float* __restrict__ out_f, int n_total) {
  constexpr int VEC = D / 64;
  const int lane = threadIdx.x & 63;
  const int n = blockIdx.x * 4 + (threadIdx.x >> 6);
  if (n >= n_total) return;
  const bool valid = n < N_NODES_C;

  float acc[VEC];
#pragma unroll
  for (int j = 0; j < VEC; ++j) acc[j] = 0.f;

  if (valid) {
    const int start = row_ptr[n];
    const int end = row_ptr[n + 1];
    for (int j0 = start; j0 < end; j0 += 64) {
      const int cnt = min(64, end - j0);
      int e = 0;
      float w = 0.f;
      if (lane < cnt) {
        e = s_src[j0 + lane];
        w = s_ew[j0 + lane];
      }
#pragma unroll 4
      for (int c = 0; c < cnt; ++c) {
        const int s = __shfl(e, c);
        const float wt = __shfl(w, c);
        if (VEC == 4) {
          uint2 v = *(const uint2*)(support + (size_t)s * D + lane * 4);
          acc[0] += bf2f(v.x & 0xffffu) * wt;
          acc[1] += bf2f(v.x >> 16) * wt;
          acc[2] += bf2f(v.y & 0xffffu) * wt;
          acc[3] += bf2f(v.y >> 16) * wt;
        } else {
          unsigned v = *(const unsigned*)(support + (size_t)s * D + lane * 2);
          acc[0] += bf2f(v & 0xffffu) * wt;
          acc[1] += bf2f(v >> 16) * wt;
        }
      }
    }
  }

  if (OUT_BF16) {
    unsigned short o[VEC];
#pragma unroll
    for (int j = 0; j < VEC; ++j) {
      if (valid) {
        float v = acc[j] + bias[lane * VEC + j];
        v = v >= 0.f ? v : NEG_SLOPE * v;
        o[j] = f2bf(v);
      } else {
        o[j] = 0;
      }
    }
    if (VEC == 4) {
      uint2 pk;
      pk.x = o[0] | ((unsigned)o[1] << 16);
      pk.y = o[2] | ((unsigned)o[3] << 16);
      *(uint2*)(out_bf + (size_t)n * D + lane * 4) = pk;
    } else {
      *(unsigned*)(out_bf + (size_t)n * D + lane * 2) = o[0] | ((unsigned)o[1] << 16);
    }
  } else {
#pragma unroll
    for (int j = 0; j < VEC; ++j) {
      float v = acc[j] + bias[lane * VEC + j];
      acc[j] = v >= 0.f ? v : NEG_SLOPE * v;
    }
    if (VEC == 2) {
      *(float2*)(out_f + (size_t)n * D + lane * 2) = make_float2(acc[0], acc[1]);
    } else {
      *(float4*)(out_f + (size_t)n * D + lane * 4) =
          make_float4(acc[0], acc[1], acc[2], acc[3]);
    }
  }
}

// ---------------- launch ----------------

extern "C" void kernel_launch(void* const* d_in, const int* in_sizes, int n_in,
                              void* d_out, int out_size, void* d_ws, size_t ws_size,
                              hipStream_t stream) {
  const float* x  = (const float*)d_in[0];   // [50000,256]
  const float* w1 = (const float*)d_in[1];   // [256,256]
  const float* b1 = (const float*)d_in[2];   // [256]
  const float* w2 = (const float*)d_in[3];   // [256,128]
  const float* b2 = (const float*)d_in[4];   // [128]
  const int*   src = (const int*)d_in[5];    // [800000]
  const int*   dst = (const int*)d_in[6];    // [800000]
  const float* ew  = (const float*)d_in[7];  // [800000]
  float* out = (float*)d_out;                // [50000,128]

  // workspace layout (bf16 tables then CSR); ~98 MB total
  unsigned short* xb   = (unsigned short*)d_ws;              // M_PAD*256
  unsigned short* a2b  = xb + (size_t)M_PAD * 256;           // M_PAD*256
  unsigned short* sup1 = a2b + (size_t)M_PAD * 256;          // M_PAD*256
  unsigned short* sup2 = sup1 + (size_t)M_PAD * 256;         // M_PAD*128
  unsigned short* w1T  = sup2 + (size_t)M_PAD * 128;         // 256*256
  unsigned short* w2T  = w1T + 256 * 256;                    // 128*256
  int* counts  = (int*)(w2T + 128 * 256);                    // 50000
  int* cursor  = counts + N_NODES_C;                         // 50000
  int* row_ptr = cursor + N_NODES_C;                         // 50001
  int* partial = row_ptr + (N_NODES_C + 1);                  // 50000
  int* blk_sums= partial + N_NODES_C;                        // 256
  int* blk_off = blk_sums + 256;                             // 256
  int* s_src   = blk_off + 256;                              // 800000
  float* s_ew  = (float*)(s_src + N_EDGES_C);                // 800000

  const int EB = (N_EDGES_C + 255) / 256;

  // CSR build (hierarchical scan replaces the 110 µs single-block scan)
  hipMemsetAsync(counts, 0, N_NODES_C * sizeof(int), stream);
  histogram_kernel<<<EB, 256, 0, stream>>>(dst, counts);
  scan_phase_a<<<N_SCAN_BLKS, 256, 0, stream>>>(counts, partial, blk_sums);
  scan_phase_b<<<1, 256, 0, stream>>>(blk_sums, blk_off);
  scan_phase_c<<<N_SCAN_BLKS, 256, 0, stream>>>(partial, blk_off, row_ptr, cursor);
  fill_kernel<<<EB, 256, 0, stream>>>(src, dst, ew, cursor, s_src, s_ew);

  // conversions
  conv_x_kernel<<<(M_PAD * 32 + 255) / 256, 256, 0, stream>>>(x, xb);
  conv_wT_kernel<<<(256 * 256 + 255) / 256, 256, 0, stream>>>(w1, w1T, 256, 256);
  conv_wT_kernel<<<(128 * 256 + 255) / 256, 256, 0, stream>>>(w2, w2T, 256, 128);

  // layer 1: support1 = x @ w1 (bf16), agg -> a2b = bf16(lrelu(agg + b1))
  gemm_bf16_kernel<<<dim3(2, M_PAD / 128), 256, 0, stream>>>(xb, w1T, sup1, 256);
  agg_kernel<256, true><<<M_PAD / 4, 256, 0, stream>>>(sup1, s_src, s_ew, row_ptr,
                                                       b1, a2b, nullptr, M_PAD);

  // layer 2: support2 = a2 @ w2 (bf16), agg -> out = lrelu(agg + b2) fp32
  gemm_bf16_kernel<<<dim3(1, M_PAD / 128), 256, 0, stream>>>(a2b, w2T, sup2, 128);
  agg_kernel<128, false><<<N_NODES_C / 4, 256, 0, stream>>>(sup2, s_src, s_ew, row_ptr,
                                                            b2, nullptr, out, N_NODES_C);
}

// Round 5
// 327.050 us; speedup vs baseline: 3.9755x; 1.1006x over previous
//
#include <hip/hip_runtime.h>

#define NEG_SLOPE 0.01f

constexpr int N_NODES_C = 50000;
constexpr int N_EDGES_C = 800000;
constexpr int M_PAD = 50048;  // 391 * 128

typedef short bf16x8 __attribute__((ext_vector_type(8)));
typedef float f32x4 __attribute__((ext_vector_type(4)));

__device__ inline unsigned short f2bf(float f) {
  unsigned int u = __float_as_uint(f);
  u += 0x7FFF + ((u >> 16) & 1);  // round-to-nearest-even
  return (unsigned short)(u >> 16);
}
__device__ inline float bf2f(unsigned int h16) {
  return __uint_as_float(h16 << 16);
}

// ---------------- CSR build ----------------

__global__ __launch_bounds__(256) void histogram_kernel(const int* __restrict__ dst,
                                                        int* __restrict__ counts) {
  int e = blockIdx.x * 256 + threadIdx.x;
  if (e < N_EDGES_C) atomicAdd(&counts[dst[e]], 1);
}

constexpr int N_SCAN_BLKS = (N_NODES_C + 255) / 256;  // 196

__global__ __launch_bounds__(256) void scan_phase_a(const int* __restrict__ counts,
                                                    int* __restrict__ partial,
                                                    int* __restrict__ blk_sums) {
  __shared__ int s[256];
  const int t = threadIdx.x;
  const int i = blockIdx.x * 256 + t;
  const int v = (i < N_NODES_C) ? counts[i] : 0;
  s[t] = v;
  __syncthreads();
  for (int off = 1; off < 256; off <<= 1) {
    int u = (t >= off) ? s[t - off] : 0;
    __syncthreads();
    s[t] += u;
    __syncthreads();
  }
  if (i < N_NODES_C) partial[i] = s[t] - v;
  if (t == 255) blk_sums[blockIdx.x] = s[255];
}

__global__ __launch_bounds__(256) void scan_phase_b(const int* __restrict__ blk_sums,
                                                    int* __restrict__ blk_off) {
  __shared__ int s[256];
  const int t = threadIdx.x;
  const int v = (t < N_SCAN_BLKS) ? blk_sums[t] : 0;
  s[t] = v;
  __syncthreads();
  for (int off = 1; off < 256; off <<= 1) {
    int u = (t >= off) ? s[t - off] : 0;
    __syncthreads();
    s[t] += u;
    __syncthreads();
  }
  if (t < N_SCAN_BLKS) blk_off[t] = s[t] - v;
}

__global__ __launch_bounds__(256) void scan_phase_c(const int* __restrict__ partial,
                                                    const int* __restrict__ blk_off,
                                                    int* __restrict__ row_ptr,
                                                    int* __restrict__ cursor) {
  const int i = blockIdx.x * 256 + threadIdx.x;
  if (i < N_NODES_C) {
    const int r = partial[i] + blk_off[blockIdx.x];
    row_ptr[i] = r;
    cursor[i] = r;
  }
  if (i == 0) row_ptr[N_NODES_C] = N_EDGES_C;
}

// meta = {src, bits(ew)} packed -> one 8B scatter store instead of two 4B
__global__ __launch_bounds__(256) void fill_kernel(const int* __restrict__ src,
                                                   const int* __restrict__ dst,
                                                   const float* __restrict__ ew,
                                                   int* __restrict__ cursor,
                                                   uint2* __restrict__ s_meta) {
  int e = blockIdx.x * 256 + threadIdx.x;
  if (e < N_EDGES_C) {
    int p = atomicAdd(&cursor[dst[e]], 1);
    uint2 m;
    m.x = (unsigned)src[e];
    m.y = __float_as_uint(ew[e]);
    s_meta[p] = m;
  }
}

// ---------------- conversions ----------------

__global__ __launch_bounds__(256) void conv_x_kernel(const float* __restrict__ x,
                                                     unsigned short* __restrict__ xb) {
  int idx = blockIdx.x * 256 + threadIdx.x;
  if (idx >= M_PAD * 32) return;
  int row = idx >> 5;
  int c8 = (idx & 31) << 3;
  uint4 v;
  if (row < N_NODES_C) {
    const float4* p = (const float4*)(x + (size_t)row * 256 + c8);
    float4 a = p[0], b = p[1];
    v.x = f2bf(a.x) | ((unsigned)f2bf(a.y) << 16);
    v.y = f2bf(a.z) | ((unsigned)f2bf(a.w) << 16);
    v.z = f2bf(b.x) | ((unsigned)f2bf(b.y) << 16);
    v.w = f2bf(b.z) | ((unsigned)f2bf(b.w) << 16);
  } else {
    v = make_uint4(0, 0, 0, 0);
  }
  *(uint4*)(xb + (size_t)row * 256 + c8) = v;
}

__global__ __launch_bounds__(256) void conv_wT_kernel(const float* __restrict__ w,
                                                      unsigned short* __restrict__ wT,
                                                      int K, int N) {
  int idx = blockIdx.x * 256 + threadIdx.x;
  if (idx >= K * N) return;
  int n = idx / K, k = idx - n * K;
  wT[idx] = f2bf(w[(size_t)k * N + n]);
}

// ---------------- bf16 MFMA GEMM (m97 structure, unchanged) ----------------

#define GLOAD_LDS16(g, l)                                              \
  __builtin_amdgcn_global_load_lds(                                    \
      (__attribute__((address_space(1))) void*)(g),                    \
      (__attribute__((address_space(3))) void*)(l), 16, 0, 0)

__global__ __launch_bounds__(256) void gemm_bf16_kernel(
    const unsigned short* __restrict__ A,   // [M_PAD][256] bf16
    const unsigned short* __restrict__ BT,  // [N][256] bf16
    unsigned short* __restrict__ C,         // [M_PAD][N] bf16
    int N) {
  constexpr int K = 256;
  __shared__ short Asm[128 * 32];
  __shared__ short Bsm[128 * 32];
  const int tid = threadIdx.x;
  const int lane = tid & 63, wave = tid >> 6;
  const int wm = wave & 1, wn = wave >> 1;
  const int row0 = blockIdx.y * 128, col0 = blockIdx.x * 128;

  const int ch0 = wave * 2, ch1 = wave * 2 + 1;
  const int o0 = ch0 * 512 + lane * 8;
  const int o1 = ch1 * 512 + lane * 8;
  const int r0 = o0 >> 5, c0 = o0 & 31;
  const int r1 = o1 >> 5, c1 = o1 & 31;

  f32x4 acc[4][4] = {};

  for (int k0 = 0; k0 < K; k0 += 32) {
    GLOAD_LDS16(A + (size_t)(row0 + r0) * K + k0 + c0, &Asm[ch0 * 512]);
    GLOAD_LDS16(A + (size_t)(row0 + r1) * K + k0 + c1, &Asm[ch1 * 512]);
    GLOAD_LDS16(BT + (size_t)(col0 + r0) * K + k0 + c0, &Bsm[ch0 * 512]);
    GLOAD_LDS16(BT + (size_t)(col0 + r1) * K + k0 + c1, &Bsm[ch1 * 512]);
    __builtin_amdgcn_s_waitcnt(0);
    __syncthreads();

    bf16x8 af[4], bf[4];
#pragma unroll
    for (int mt = 0; mt < 4; ++mt)
      af[mt] = *(const bf16x8*)&Asm[(wm * 64 + mt * 16 + (lane & 15)) * 32 + (lane >> 4) * 8];
#pragma unroll
    for (int nt = 0; nt < 4; ++nt)
      bf[nt] = *(const bf16x8*)&Bsm[(wn * 64 + nt * 16 + (lane & 15)) * 32 + (lane >> 4) * 8];
#pragma unroll
    for (int mt = 0; mt < 4; ++mt)
#pragma unroll
      for (int nt = 0; nt < 4; ++nt)
        acc[mt][nt] = __builtin_amdgcn_mfma_f32_16x16x32_bf16(af[mt], bf[nt], acc[mt][nt], 0, 0, 0);
    __syncthreads();
  }

  const int cl = lane & 15, rq = (lane >> 4) * 4;
#pragma unroll
  for (int mt = 0; mt < 4; ++mt) {
    const int rbase = row0 + wm * 64 + mt * 16 + rq;
#pragma unroll
    for (int nt = 0; nt < 4; ++nt) {
      const int col = col0 + wn * 64 + nt * 16 + cl;
#pragma unroll
      for (int i = 0; i < 4; ++i)
        C[(size_t)(rbase + i) * N + col] = f2bf(acc[mt][nt][i]);
    }
  }
}

// ---------------- gather aggregation, wave-per-node, multi-edge per load ----------------
// D=256: 32 lanes/row (uint4 = 8 bf16), 2 edges per wave-load
// D=128: 16 lanes/row (uint4 = 8 bf16), 4 edges per wave-load
// out[n,:] = (lrelu)(bias + sum_e support[src_e,:]*ew_e)

template <int D, bool OUT_BF16>
__global__ __launch_bounds__(256) void agg_kernel(
    const unsigned short* __restrict__ support, const uint2* __restrict__ s_meta,
    const int* __restrict__ row_ptr, const float* __restrict__ bias,
    unsigned short* __restrict__ out_bf, float* __restrict__ out_f, int n_total) {
  constexpr int G = D / 8;      // lanes per row: 32 (D=256) / 16 (D=128)
  constexpr int EPW = 64 / G;   // edges per iteration: 2 / 4
  const int lane = threadIdx.x & 63;
  const int sub = lane / G;
  const int li = lane % G;      // 8 dims per lane: [li*8, li*8+8)
  const int n = blockIdx.x * 4 + (threadIdx.x >> 6);
  if (n >= n_total) return;
  const bool valid = n < N_NODES_C;

  float acc[8] = {};

  if (valid) {
    const int start = row_ptr[n];
    const int end = row_ptr[n + 1];
    for (int j0 = start; j0 < end; j0 += 64) {
      const int cnt = min(64, end - j0);
      int e = 0;
      float w = 0.f;
      if (lane < cnt) {
        uint2 m = s_meta[j0 + lane];
        e = (int)m.x;
        w = __uint_as_float(m.y);
      }
      const int nIter = (cnt + EPW - 1) / EPW;
#pragma unroll 8
      for (int c = 0; c < nIter; ++c) {
        const int slot = c * EPW + sub;
        const int s = __shfl(e, slot);
        const float wt = __shfl(w, slot);
        uint4 v = *(const uint4*)(support + (size_t)s * D + li * 8);
        acc[0] += bf2f(v.x & 0xffffu) * wt;
        acc[1] += bf2f(v.x >> 16) * wt;
        acc[2] += bf2f(v.y & 0xffffu) * wt;
        acc[3] += bf2f(v.y >> 16) * wt;
        acc[4] += bf2f(v.z & 0xffffu) * wt;
        acc[5] += bf2f(v.z >> 16) * wt;
        acc[6] += bf2f(v.w & 0xffffu) * wt;
        acc[7] += bf2f(v.w >> 16) * wt;
      }
    }
  }

  // cross-subgroup reduction: lanes sharing li sum their partials
#pragma unroll
  for (int j = 0; j < 8; ++j) {
    acc[j] += __shfl_xor(acc[j], 32);
    if (G == 16) acc[j] += __shfl_xor(acc[j], 16);
  }

  if (OUT_BF16) {
    if (sub == 0) {
      unsigned short o[8];
#pragma unroll
      for (int j = 0; j < 8; ++j) {
        if (valid) {
          float v = acc[j] + bias[li * 8 + j];
          v = v >= 0.f ? v : NEG_SLOPE * v;
          o[j] = f2bf(v);
        } else {
          o[j] = 0;
        }
      }
      uint4 pk;
      pk.x = o[0] | ((unsigned)o[1] << 16);
      pk.y = o[2] | ((unsigned)o[3] << 16);
      pk.z = o[4] | ((unsigned)o[5] << 16);
      pk.w = o[6] | ((unsigned)o[7] << 16);
      *(uint4*)(out_bf + (size_t)n * D + li * 8) = pk;
    }
  } else {
    if (valid && sub == 0) {
      float r[8];
#pragma unroll
      for (int j = 0; j < 8; ++j) {
        float v = acc[j] + bias[li * 8 + j];
        r[j] = v >= 0.f ? v : NEG_SLOPE * v;
      }
      *(float4*)(out_f + (size_t)n * D + li * 8) = make_float4(r[0], r[1], r[2], r[3]);
      *(float4*)(out_f + (size_t)n * D + li * 8 + 4) = make_float4(r[4], r[5], r[6], r[7]);
    }
  }
}

// ---------------- launch ----------------

extern "C" void kernel_launch(void* const* d_in, const int* in_sizes, int n_in,
                              void* d_out, int out_size, void* d_ws, size_t ws_size,
                              hipStream_t stream) {
  const float* x  = (const float*)d_in[0];   // [50000,256]
  const float* w1 = (const float*)d_in[1];   // [256,256]
  const float* b1 = (const float*)d_in[2];   // [256]
  const float* w2 = (const float*)d_in[3];   // [256,128]
  const float* b2 = (const float*)d_in[4];   // [128]
  const int*   src = (const int*)d_in[5];    // [800000]
  const int*   dst = (const int*)d_in[6];    // [800000]
  const float* ew  = (const float*)d_in[7];  // [800000]
  float* out = (float*)d_out;                // [50000,128]

  unsigned short* xb   = (unsigned short*)d_ws;              // M_PAD*256
  unsigned short* a2b  = xb + (size_t)M_PAD * 256;           // M_PAD*256
  unsigned short* sup1 = a2b + (size_t)M_PAD * 256;          // M_PAD*256
  unsigned short* sup2 = sup1 + (size_t)M_PAD * 256;         // M_PAD*128
  unsigned short* w1T  = sup2 + (size_t)M_PAD * 128;         // 256*256
  unsigned short* w2T  = w1T + 256 * 256;                    // 128*256
  int* counts  = (int*)(w2T + 128 * 256);                    // 50000
  int* cursor  = counts + N_NODES_C;                         // 50000
  int* row_ptr = cursor + N_NODES_C;                         // 50001
  int* partial = row_ptr + (N_NODES_C + 1);                  // 50000
  int* blk_sums= partial + N_NODES_C;                        // 256
  int* blk_off = blk_sums + 256;                             // 256
  uint2* s_meta = (uint2*)(blk_off + 256 + 2);               // 800000 * 8B (8B aligned)

  const int EB = (N_EDGES_C + 255) / 256;

  // CSR build
  hipMemsetAsync(counts, 0, N_NODES_C * sizeof(int), stream);
  histogram_kernel<<<EB, 256, 0, stream>>>(dst, counts);
  scan_phase_a<<<N_SCAN_BLKS, 256, 0, stream>>>(counts, partial, blk_sums);
  scan_phase_b<<<1, 256, 0, stream>>>(blk_sums, blk_off);
  scan_phase_c<<<N_SCAN_BLKS, 256, 0, stream>>>(partial, blk_off, row_ptr, cursor);
  fill_kernel<<<EB, 256, 0, stream>>>(src, dst, ew, cursor, s_meta);

  // conversions
  conv_x_kernel<<<(M_PAD * 32 + 255) / 256, 256, 0, stream>>>(x, xb);
  conv_wT_kernel<<<(256 * 256 + 255) / 256, 256, 0, stream>>>(w1, w1T, 256, 256);
  conv_wT_kernel<<<(128 * 256 + 255) / 256, 256, 0, stream>>>(w2, w2T, 256, 128);

  // layer 1
  gemm_bf16_kernel<<<dim3(2, M_PAD / 128), 256, 0, stream>>>(xb, w1T, sup1, 256);
  agg_kernel<256, true><<<M_PAD / 4, 256, 0, stream>>>(sup1, s_meta, row_ptr,
                                                       b1, a2b, nullptr, M_PAD);

  // layer 2
  gemm_bf16_kernel<<<dim3(1, M_PAD / 128), 256, 0, stream>>>(a2b, w2T, sup2, 128);
  agg_kernel<128, false><<<N_NODES_C / 4, 256, 0, stream>>>(sup2, s_meta, row_ptr,
                                                            b2, nullptr, out, N_NODES_C);
}